// Round 16
// baseline (97.582 us; speedup 1.0000x reference)
//
#include <hip/hip_runtime.h>

// LIF neuron scan: v = v*0.5 + x[t]; s = (v - 0.5 > 0); v -= s*0.5
// Round 15 -> 16: decisive A/B on the WRITE stream. R13/R14/R15 falsified the
// occupancy/latency/phase-lock theories (all ~90-100us). Bytes aren't the
// wall (R15 actual HBM ~315MB -> 45us at the fill kernel's 7 TB/s). Remaining
// suspect: stream shape. R14-K2's grid-stride swept the bits region 25x
// (8.4MB x 25 = 210MB of L2/L3 re-reads) with 2048 blocks. New K2 is
// EXACTLY fill-shaped (the kernel measured at 7 TB/s): 51200 one-shot blocks
// x 256 threads, one f4 store per thread, each block reads its ~41 bits-words
// once (bits traffic 8.4MB total). K1 = R14's lif_walk verbatim (proven).
// Fallback single kernel (R13, proven 91us) if ws_size too small.

#define T_STEPS 100
#define T_VEC   25      // f4 per row in global
#define ROWS    64      // rows per block == blockDim.x (one wave), K1
#define CA      12      // pass-A f4 chunks (48 steps)
#define CB      13      // pass-B f4 chunks (52 steps)
#define LSTRIDE 13      // K1 tile row stride in f4
#define DECAY   0.5f
#define VTH     0.5f

typedef float vfloat4 __attribute__((ext_vector_type(4)));

// ---------------- K1: coalesced load -> LDS -> walk -> packed bits ----------
__global__ __launch_bounds__(64, 3) void lif_walk(const float* __restrict__ x,
                                                  uint4* __restrict__ bitsg,
                                                  int n_rows) {
    __shared__ vfloat4 tile[ROWS * LSTRIDE];   // 13,312 B

    const int lane = threadIdx.x;
    const int row0 = blockIdx.x * ROWS;
    const int gf0 = row0 * T_VEC;
    const int total_f4 = n_rows * T_VEC;

    const vfloat4* __restrict__ xb = reinterpret_cast<const vfloat4*>(x);
    const vfloat4 vzero = {0.0f, 0.0f, 0.0f, 0.0f};

    // Pass A stage: coalesced loads (64 rows x 12 f4) -> tile
    {
        vfloat4 st[CA];
        #pragma unroll
        for (int k = 0; k < CA; ++k) {
            int f = k * 64 + lane;                   // 0..767
            int r = f / CA, c = f % CA;
            int g = gf0 + r * T_VEC + c;
            st[k] = (g < total_f4) ? xb[g] : vzero;
        }
        #pragma unroll
        for (int k = 0; k < CA; ++k) {
            int f = k * 64 + lane;
            int r = f / CA, c = f % CA;
            tile[r * LSTRIDE + c] = st[k];
        }
    }
    __syncthreads();   // stage-A writes visible before walk-A reads

    // Pass B loads issued now; latency hides under pass-A walk
    vfloat4 sb[CB];
    #pragma unroll
    for (int k = 0; k < CB; ++k) {
        int f = k * 64 + lane;                       // 0..831
        int r = f / CB, c = f % CB;
        int g = gf0 + r * T_VEC + CA + c;
        sb[k] = (g < total_f4) ? xb[g] : vzero;
    }
    __builtin_amdgcn_sched_barrier(0);               // pin: loads issue first

    // Walk pass A: 48 serial steps, pack bits
    unsigned int pk0 = 0, pk1 = 0, pk2 = 0, pk3 = 0;
    float v = 0.0f;
    #pragma unroll
    for (int c = 0; c < CA; ++c) {
        vfloat4 xs = tile[lane * LSTRIDE + c];
        #pragma unroll
        for (int k = 0; k < 4; ++k) {
            // v*0.5 exact (pow2); conditional -0.5 exact -> bitwise == ref.
            v = v * DECAY + xs[k];
            bool s = (v - VTH > 0.0f);
            v -= s ? VTH : 0.0f;
            unsigned int bit = s ? 1u : 0u;
            const int b = c * 4 + k;                 // 0..47
            if (b < 32) pk0 |= bit << b;
            else        pk1 |= bit << (b - 32);
        }
    }
    __syncthreads();   // WAR: walk-A reads done before stage-B overwrites

    // Pass B stage
    #pragma unroll
    for (int k = 0; k < CB; ++k) {
        int f = k * 64 + lane;
        int r = f / CB, c = f % CB;
        tile[r * LSTRIDE + c] = sb[k];
    }
    __syncthreads();   // RAW: stage-B writes before walk-B reads

    // Walk pass B: 52 serial steps
    #pragma unroll
    for (int c = 0; c < CB; ++c) {
        vfloat4 xs = tile[lane * LSTRIDE + c];
        #pragma unroll
        for (int k = 0; k < 4; ++k) {
            v = v * DECAY + xs[k];
            bool s = (v - VTH > 0.0f);
            v -= s ? VTH : 0.0f;
            unsigned int bit = s ? 1u : 0u;
            const int b = 48 + c * 4 + k;            // 48..99
            if (b < 64)      pk1 |= bit << (b - 32);
            else if (b < 96) pk2 |= bit << (b - 64);
            else             pk3 |= bit << (b - 96);
        }
    }

    // Coalesced 16B/row bits store (rows consecutive -> 1KB per wave store)
    if (row0 + lane < n_rows) {
        uint4 w; w.x = pk0; w.y = pk1; w.z = pk2; w.w = pk3;
        bitsg[row0 + lane] = w;
    }
}

// ---------------- K2: fill-shaped expander -----------------------------------
// One f4 store per thread, one-shot blocks (51200), block-local bits reads
// (each 16B bits-line feeds 400B of output; bits traffic 8.4MB total).
__global__ __launch_bounds__(256) void lif_expand(const unsigned int* __restrict__ bw,
                                                  vfloat4* __restrict__ ob,
                                                  int total_f4) {
    int f = blockIdx.x * 256 + threadIdx.x;
    if (f >= total_f4) return;
    int r  = f / T_VEC;                  // magic-mul
    int c4 = f % T_VEC;
    unsigned int word = bw[r * 4 + (c4 >> 3)];      // L1-broadcast heavy
    unsigned int nib = (word >> ((c4 & 7) * 4)) & 0xFu;
    vfloat4 s;
    s.x = (nib & 1u) ? 1.0f : 0.0f;
    s.y = (nib & 2u) ? 1.0f : 0.0f;
    s.z = (nib & 4u) ? 1.0f : 0.0f;
    s.w = (nib & 8u) ? 1.0f : 0.0f;
    ob[f] = s;
}

// ---------------- Fallback: R13 single kernel (ws too small) ----------------
__global__ __launch_bounds__(64, 3) void lif_kernel(const float* __restrict__ x,
                                                    float* __restrict__ out,
                                                    int n_rows) {
    __shared__ vfloat4 tile[ROWS * LSTRIDE];
    __shared__ unsigned int bits[ROWS * 4];

    const int lane = threadIdx.x;
    const int row0 = blockIdx.x * ROWS;
    const int gf0 = row0 * T_VEC;
    const int total_f4 = n_rows * T_VEC;

    const vfloat4* __restrict__ xb = reinterpret_cast<const vfloat4*>(x);
    const vfloat4 vzero = {0.0f, 0.0f, 0.0f, 0.0f};

    {
        vfloat4 st[CA];
        #pragma unroll
        for (int k = 0; k < CA; ++k) {
            int f = k * 64 + lane;
            int r = f / CA, c = f % CA;
            int g = gf0 + r * T_VEC + c;
            st[k] = (g < total_f4) ? xb[g] : vzero;
        }
        #pragma unroll
        for (int k = 0; k < CA; ++k) {
            int f = k * 64 + lane;
            int r = f / CA, c = f % CA;
            tile[r * LSTRIDE + c] = st[k];
        }
    }
    __syncthreads();

    vfloat4 sb[CB];
    #pragma unroll
    for (int k = 0; k < CB; ++k) {
        int f = k * 64 + lane;
        int r = f / CB, c = f % CB;
        int g = gf0 + r * T_VEC + CA + c;
        sb[k] = (g < total_f4) ? xb[g] : vzero;
    }
    __builtin_amdgcn_sched_barrier(0);

    unsigned int pk0 = 0, pk1 = 0, pk2 = 0, pk3 = 0;
    float v = 0.0f;
    #pragma unroll
    for (int c = 0; c < CA; ++c) {
        vfloat4 xs = tile[lane * LSTRIDE + c];
        #pragma unroll
        for (int k = 0; k < 4; ++k) {
            v = v * DECAY + xs[k];
            bool s = (v - VTH > 0.0f);
            v -= s ? VTH : 0.0f;
            unsigned int bit = s ? 1u : 0u;
            const int b = c * 4 + k;
            if (b < 32) pk0 |= bit << b;
            else        pk1 |= bit << (b - 32);
        }
    }
    __syncthreads();

    #pragma unroll
    for (int k = 0; k < CB; ++k) {
        int f = k * 64 + lane;
        int r = f / CB, c = f % CB;
        tile[r * LSTRIDE + c] = sb[k];
    }
    __syncthreads();

    #pragma unroll
    for (int c = 0; c < CB; ++c) {
        vfloat4 xs = tile[lane * LSTRIDE + c];
        #pragma unroll
        for (int k = 0; k < 4; ++k) {
            v = v * DECAY + xs[k];
            bool s = (v - VTH > 0.0f);
            v -= s ? VTH : 0.0f;
            unsigned int bit = s ? 1u : 0u;
            const int b = 48 + c * 4 + k;
            if (b < 64)      pk1 |= bit << (b - 32);
            else if (b < 96) pk2 |= bit << (b - 64);
            else             pk3 |= bit << (b - 96);
        }
    }

    {
        uint4 w; w.x = pk0; w.y = pk1; w.z = pk2; w.w = pk3;
        reinterpret_cast<uint4*>(bits)[lane] = w;
    }
    __syncthreads();

    vfloat4* __restrict__ ob = reinterpret_cast<vfloat4*>(out);
    #pragma unroll
    for (int i = 0; i < T_VEC; ++i) {
        int f = i * 64 + lane;
        int g = gf0 + f;
        if (g < total_f4) {
            int r  = f / T_VEC;
            int c4 = f % T_VEC;
            unsigned int word = bits[r * 4 + (c4 >> 3)];
            unsigned int nib = (word >> ((c4 & 7) * 4)) & 0xFu;
            vfloat4 s;
            s.x = (nib & 1u) ? 1.0f : 0.0f;
            s.y = (nib & 2u) ? 1.0f : 0.0f;
            s.z = (nib & 4u) ? 1.0f : 0.0f;
            s.w = (nib & 8u) ? 1.0f : 0.0f;
            ob[g] = s;
        }
    }
}

extern "C" void kernel_launch(void* const* d_in, const int* in_sizes, int n_in,
                              void* d_out, int out_size, void* d_ws, size_t ws_size,
                              hipStream_t stream) {
    const float* x = (const float*)d_in[0];
    float* out = (float*)d_out;

    int n_rows = in_sizes[0] / T_STEPS;              // 32 * 16384 = 524288
    int total_f4 = n_rows * T_VEC;                   // 13,107,200
    int grid1 = (n_rows + ROWS - 1) / ROWS;          // 8192

    size_t need = (size_t)n_rows * 16;               // 8.4 MB of packed bits
    if (ws_size >= need) {
        int grid2 = (total_f4 + 255) / 256;          // 51,200 one-shot blocks
        lif_walk<<<grid1, ROWS, 0, stream>>>(x, (uint4*)d_ws, n_rows);
        lif_expand<<<grid2, 256, 0, stream>>>((const unsigned int*)d_ws,
                                              (vfloat4*)out, total_f4);
    } else {
        lif_kernel<<<grid1, ROWS, 0, stream>>>(x, out, n_rows);
    }
}